// Round 1
// 803.050 us; speedup vs baseline: 1.2256x; 1.2256x over previous
//
#include <hip/hip_runtime.h>
#include <stdint.h>

#define WIN 14
#define HW 196
#define NH 12
#define HIDDEN 768
#define BH 3072
#define MTOT 50176
#define KDIM 768

typedef __bf16 bf16x8 __attribute__((ext_vector_type(8)));
typedef float f32x4 __attribute__((ext_vector_type(4)));

__device__ __forceinline__ float bf2f(uint16_t u) {
  union { uint32_t i; float f; } v; v.i = ((uint32_t)u) << 16; return v.f;
}
__device__ __forceinline__ uint16_t f2bf(float f) {
  uint32_t u = __float_as_uint(f);
  uint32_t r = u + 0x7FFFu + ((u >> 16) & 1u);
  return (uint16_t)(r >> 16);
}
__device__ __forceinline__ uint32_t pack2bf(float a, float b) {
  return (uint32_t)f2bf(a) | ((uint32_t)f2bf(b) << 16);
}
__device__ __forceinline__ f32x4 mfma16(bf16x8 a, bf16x8 b, f32x4 c) {
  return __builtin_amdgcn_mfma_f32_16x16x32_bf16(a, b, c, 0, 0, 0);
}
__device__ __forceinline__ f32x4 f4zero() { f32x4 z = {0.f, 0.f, 0.f, 0.f}; return z; }

__device__ __forceinline__ void async16(const void* g, void* l) {
#if __has_builtin(__builtin_amdgcn_global_load_lds)
  __builtin_amdgcn_global_load_lds((__attribute__((address_space(1))) void*)g,
                                   (__attribute__((address_space(3))) void*)l, 16, 0, 0);
#else
  *(uint4*)l = *(const uint4*)g;
#endif
}

// ---------------- fp32 -> bf16 convert ----------------
__global__ __launch_bounds__(256) void cvt_bf16(const float* __restrict__ in,
                                                uint16_t* __restrict__ out, int n4) {
  int i = blockIdx.x * blockDim.x + threadIdx.x;
  const int stride = gridDim.x * blockDim.x;
  for (; i < n4; i += stride) {
    float4 v = ((const float4*)in)[i];
    ushort4 o;
    o.x = f2bf(v.x); o.y = f2bf(v.y); o.z = f2bf(v.z); o.w = f2bf(v.w);
    ((ushort4*)out)[i] = o;
  }
}

// ---------------- build rel-pos B-operand table: Rt[64][64] bf16 ----------------
// rows 0..26 = rel_pos_h * 8, rows 32..58 = rel_pos_w * 8, rest zero.
__global__ __launch_bounds__(256) void build_rt(const float* __restrict__ rh,
                                                const float* __restrict__ rw,
                                                uint16_t* __restrict__ Rt) {
  const int i = blockIdx.x * 256 + threadIdx.x;
  if (i < 4096) {
    const int r = i >> 6, c = i & 63;
    float v = 0.f;
    if (r < 27) v = rh[r * 64 + c] * 8.f;
    else if (r >= 32 && r < 59) v = rw[(r - 32) * 64 + c] * 8.f;
    Rt[i] = f2bf(v);
  }
}

// ---------------- GEMM: C[m][n] = sum_k A[m][k]*B[n][k] (+bias), bf16 in, K=768 ----
// EPI 0: scatter qkv bf16 (q pre-scaled by 0.125); EPI 1: fp32 out row-major.
// XCD-aware block swizzle: blocks sharing an A-panel (same m-tile row) land on the
// same XCD's L2 (total blocks % 8 == 0 for both instantiations: 7056, 2352).
template <int EPI>
__global__ __launch_bounds__(256) void gemm_bt(const uint16_t* __restrict__ A,
                                               const uint16_t* __restrict__ B,
                                               const float* __restrict__ bias,
                                               void* __restrict__ outp) {
  __shared__ __align__(16) uint16_t As[128 * 64];
  __shared__ __align__(16) uint16_t Bs[128 * 64];
  const int tid = threadIdx.x;
  const int nbx = gridDim.x;
  const int total = nbx * gridDim.y;
  const int id0 = blockIdx.y * nbx + blockIdx.x;
  int bxx = blockIdx.x, byy = blockIdx.y;
  if ((total & 7) == 0) {
    const int chunkq = total >> 3;
    const int idr = (id0 & 7) * chunkq + (id0 >> 3);
    bxx = idr % nbx;
    byy = idr / nbx;
  }
  const int tile_n = bxx * 128;
  const int tile_m = byy * 128;
  const int wave = tid >> 6, lane = tid & 63;
  const int l15 = lane & 15, quad = lane >> 4;
  const int wm = (wave & 1) * 64, wn = (wave >> 1) * 64;

  f32x4 acc[4][4];
#pragma unroll
  for (int mi = 0; mi < 4; mi++)
#pragma unroll
    for (int ni = 0; ni < 4; ni++) acc[mi][ni] = f4zero();

  for (int k0 = 0; k0 < KDIM; k0 += 64) {
    // XOR-swizzled staging: chunk (r,c) lives at lds r*128 + (c^(r&7))*16
#pragma unroll
    for (int i = 0; i < 4; i++) {
      const int o = tid * 16 + i * 4096;
      const int r = o >> 7;
      const int c = ((o >> 4) & 7) ^ (r & 7);
      async16((const uint8_t*)A + ((size_t)(tile_m + r) * KDIM + k0 + c * 8) * 2,
              (uint8_t*)As + o);
    }
#pragma unroll
    for (int i = 0; i < 4; i++) {
      const int o = tid * 16 + i * 4096;
      const int r = o >> 7;
      const int c = ((o >> 4) & 7) ^ (r & 7);
      async16((const uint8_t*)B + ((size_t)(tile_n + r) * KDIM + k0 + c * 8) * 2,
              (uint8_t*)Bs + o);
    }
    __syncthreads();
#pragma unroll
    for (int kk = 0; kk < 2; kk++) {
      bf16x8 af[4], bfr[4];
#pragma unroll
      for (int mi = 0; mi < 4; mi++) {
        const int r = wm + mi * 16 + l15;
        const int c = (kk * 4 + quad) ^ (r & 7);
        af[mi] = *(const bf16x8*)(As + r * 64 + c * 8);
      }
#pragma unroll
      for (int ni = 0; ni < 4; ni++) {
        const int r = wn + ni * 16 + l15;
        const int c = (kk * 4 + quad) ^ (r & 7);
        bfr[ni] = *(const bf16x8*)(Bs + r * 64 + c * 8);
      }
#pragma unroll
      for (int mi = 0; mi < 4; mi++)
#pragma unroll
        for (int ni = 0; ni < 4; ni++)
          acc[mi][ni] = mfma16(af[mi], bfr[ni], acc[mi][ni]);
    }
    __syncthreads();
  }

#pragma unroll
  for (int mi = 0; mi < 4; mi++) {
#pragma unroll
    for (int ni = 0; ni < 4; ni++) {
#pragma unroll
      for (int rg = 0; rg < 4; rg++) {
        const int m = tile_m + wm + mi * 16 + quad * 4 + rg;
        const int n = tile_n + wn + ni * 16 + l15;
        float v = acc[mi][ni][rg] + bias[n];
        if (EPI == 0) {
          const int which = n / HIDDEN;
          const int rem = n - which * HIDDEN;
          const int head = rem >> 6, d = rem & 63;
          const int b = m / HW;
          const int s = m - b * HW;
          if (which == 0) v *= 0.125f;  // q pre-scaled by hd^-0.5
          ((uint16_t*)outp)[(((size_t)which * BH + (size_t)b * NH + head) * HW + s) * 64 + d] =
              f2bf(v);
        } else {
          ((float*)outp)[(size_t)m * HIDDEN + n] = v;
        }
      }
    }
  }
}

// ---------------- fused attention (swapped-operand form) ----------------
// One block = (bh, 64-row q tile). S computed as mfma(K,Q) so each lane owns one
// q-row (q = wave*16 + l15); softmax reduces across quads only (2 shuffles).
// P stays in registers: PV contraction uses a permuted j-order (kappa) so the
// A-fragment for chunk (ks,quad) is exactly the lane's own p-values; V^T is
// written into LDS directly in kappa-order with an XOR-chunk swizzle that is
// conflict-free for both the scalar transpose writes and the b128 PV reads.
// LDS: Ks[208][64] (swizzled, 26624B) overlaid later by Vt[64][224] (28672B),
// plus Ts[64][68] (8704B) => 37376B => 4 blocks/CU.
__global__ __launch_bounds__(256, 4) void attn_kernel(const uint16_t* __restrict__ qkv,
                                                      const uint16_t* __restrict__ Rt,
                                                      uint16_t* __restrict__ aout) {
  __shared__ __align__(16) uint8_t smem[37376];
  uint16_t* Ks = (uint16_t*)smem;              // [208][64] chunk-swizzled
  uint16_t* Vt = (uint16_t*)smem;              // [64][224] kappa-order, chunk-swizzled
  uint16_t* Ts = (uint16_t*)(smem + 28672);    // [64][68]: T^T[r][q_local]

  const int wgid = blockIdx.x;                 // 0..12287
  const int jsw = (wgid & 7) * 1536 + (wgid >> 3);  // XCD swizzle (12288 % 8 == 0)
  const int qt = jsw & 3;
  const int bh = jsw >> 2;
  const int q0 = qt * 64;
  const int tid = threadIdx.x;
  const int wave = tid >> 6, lane = tid & 63;
  const int l15 = lane & 15, quad = lane >> 4;

  const uint16_t* qg = qkv + (size_t)bh * HW * 64;
  const uint16_t* kg = qkv + ((size_t)BH + bh) * HW * 64;
  const uint16_t* vg = qkv + ((size_t)2 * BH + bh) * HW * 64;

  // ---- stage K -> Ks, chunk-swizzled: (r, chunk c) at r*64 + (c^(r&7))*8
#pragma unroll
  for (int i = 0; i < 7; i++) {
    const int c = tid + i * 256;
    if (c < 1568) {
      const int r = c >> 3, ch = c & 7;
      uint4 v = *(const uint4*)(kg + (size_t)r * 64 + ch * 8);
      *(uint4*)(Ks + r * 64 + ((ch ^ (r & 7)) * 8)) = v;
    }
  }

  // ---- Q fragment straight from global (b-operand: row=l15, chunk=quad)
  const int qrow = q0 + wave * 16 + l15;       // this lane's q row
  const int qr = (qrow < HW) ? qrow : (HW - 1);
  bf16x8 qb0 = *(const bf16x8*)(qg + (size_t)qr * 64 + quad * 8);
  bf16x8 qb1 = *(const bf16x8*)(qg + (size_t)qr * 64 + 32 + quad * 8);

  // ---- T^T = Rt * Q^T : lane holds T^T[r = t*16+quad*4+rg][q=l15]; spill to Ts
  {
    f32x4 racc[4];
#pragma unroll
    for (int t = 0; t < 4; t++) racc[t] = f4zero();
    __builtin_amdgcn_s_setprio(1);
#pragma unroll
    for (int t = 0; t < 4; t++) {
      bf16x8 r0 = *(const bf16x8*)(Rt + (t * 16 + l15) * 64 + quad * 8);
      bf16x8 r1 = *(const bf16x8*)(Rt + (t * 16 + l15) * 64 + 32 + quad * 8);
      racc[t] = mfma16(r0, qb0, racc[t]);
      racc[t] = mfma16(r1, qb1, racc[t]);
    }
    __builtin_amdgcn_s_setprio(0);
#pragma unroll
    for (int t = 0; t < 4; t++)
#pragma unroll
      for (int rg = 0; rg < 4; rg++)
        Ts[(t * 16 + quad * 4 + rg) * 68 + wave * 16 + l15] = f2bf(racc[t][rg]);
  }

  __syncthreads();  // Ks staged (Ts writes also ordered before all later reads)

  // ---- prefetch V into registers (latency hidden under S-phase MFMAs)
  uint4 vreg[7];
#pragma unroll
  for (int i = 0; i < 7; i++) {
    const int c = tid + i * 256;
    vreg[i] = (c < 1568) ? *(const uint4*)(vg + (size_t)c * 8) : make_uint4(0u, 0u, 0u, 0u);
  }

  // ---- S^T = K * Q^T : lane holds S[j = t*16+quad*4+rg][its own q]
  f32x4 sacc[13];
#pragma unroll
  for (int t = 0; t < 13; t++) sacc[t] = f4zero();
  {
    const int sw0 = (quad ^ (l15 & 7)) * 8;
    const int sw1 = ((quad + 4) ^ (l15 & 7)) * 8;
    __builtin_amdgcn_s_setprio(1);
#pragma unroll
    for (int t = 0; t < 13; t++) {
      const uint16_t* kr = Ks + (t * 16 + l15) * 64;
      bf16x8 a0 = *(const bf16x8*)(kr + sw0);
      bf16x8 a1 = *(const bf16x8*)(kr + sw1);
      sacc[t] = mfma16(a0, qb0, sacc[t]);
      sacc[t] = mfma16(a1, qb1, sacc[t]);
    }
    __builtin_amdgcn_s_setprio(0);
  }

  __syncthreads();  // all waves done reading Ks; V loads drained before overlay

  // ---- zero the kappa-tail columns [196,224) of Vt (one store per thread)
  {
    const int d = tid & 63, wv = tid >> 6;
    if (wv == 0) *(uint2*)(Vt + d * 224 + 196) = make_uint2(0u, 0u);
    else *(uint4*)(Vt + d * 224 + 200 + (wv - 1) * 8) = make_uint4(0u, 0u, 0u, 0u);
  }

  // ---- V^T into Vt in kappa-order, swizzled; writes are bank-conflict-free
  // kappa(j): j = t*16 + qj*4 + rg  ->  (t>>1)*32 + qj*8 + (t&1)*4 + rg
#pragma unroll
  for (int i = 0; i < 7; i++) {
    const int c = tid + i * 256;
    if (c < 1568) {
      const int jj = c >> 3;
      const int dp = c & 7;               // d block: rows dp*8 .. dp*8+7
      const int tt = jj >> 4;
      const int kap = (tt >> 1) * 32 + ((jj >> 2) & 3) * 8 + (tt & 1) * 4 + (jj & 3);
      const int cj = kap >> 3;
      const int chs = (cj < 24) ? ((cj & 24) | ((cj & 7) ^ dp)) : cj;
      uint16_t* dst = Vt + dp * 8 * 224 + chs * 8 + (kap & 7);
      const uint16_t* pe = (const uint16_t*)&vreg[i];
#pragma unroll
      for (int e = 0; e < 8; e++) dst[e * 224] = pe[e];
    }
  }

  // ---- softmax fully in registers (row = lane's own q); bias from Ts
  uint32_t P2[13][2];
  {
    const int hq = (qr * 586) >> 13;      // qr / 14
    const int wq = qr - hq * 14;
    const uint16_t* Tb = Ts + wave * 16 + l15;   // column base, rows stride 68
    const int c0 = (hq + 13) * 68;
    const int c1 = (wq + 45) * 68;
    float mx0 = -1e30f, mx1 = -1e30f, mx2 = -1e30f, mx3 = -1e30f;
#pragma unroll
    for (int t = 0; t < 13; t++) {
#pragma unroll
      for (int rg = 0; rg < 4; rg++) {
        const int j = t * 16 + quad * 4 + rg;
        const int kh = (j * 586) >> 13;   // j / 14 (valid for j <= 195)
        const int kw = j - kh * 14;
        const float b = bf2f(Tb[c0 - kh * 68]) + bf2f(Tb[c1 - kw * 68]);
        float s = sacc[t][rg] + b;
        s = (j < HW) ? s : -1e30f;
        sacc[t][rg] = s;
        if (rg == 0) mx0 = fmaxf(mx0, s);
        else if (rg == 1) mx1 = fmaxf(mx1, s);
        else if (rg == 2) mx2 = fmaxf(mx2, s);
        else mx3 = fmaxf(mx3, s);
      }
    }
    float mx = fmaxf(fmaxf(mx0, mx1), fmaxf(mx2, mx3));
    mx = fmaxf(mx, __shfl_xor(mx, 16, 64));
    mx = fmaxf(mx, __shfl_xor(mx, 32, 64));
    float s0 = 0.f, s1 = 0.f, s2 = 0.f, s3 = 0.f;
#pragma unroll
    for (int t = 0; t < 13; t++) {
#pragma unroll
      for (int rg = 0; rg < 4; rg++) {
        const float p = __expf(sacc[t][rg] - mx);
        sacc[t][rg] = p;
        if (rg == 0) s0 += p;
        else if (rg == 1) s1 += p;
        else if (rg == 2) s2 += p;
        else s3 += p;
      }
    }
    float sum = (s0 + s1) + (s2 + s3);
    sum += __shfl_xor(sum, 16, 64);
    sum += __shfl_xor(sum, 32, 64);
    const float inv = 1.f / sum;
#pragma unroll
    for (int t = 0; t < 13; t++) {
      P2[t][0] = pack2bf(sacc[t][0] * inv, sacc[t][1] * inv);
      P2[t][1] = pack2bf(sacc[t][2] * inv, sacc[t][3] * inv);
    }
  }

  __syncthreads();  // all Vt writes visible before PV reads

  // ---- O = P*V : A-fragment is the lane's own P2 registers (kappa order)
  f32x4 oacc[4];
#pragma unroll
  for (int nt = 0; nt < 4; nt++) oacc[nt] = f4zero();
  {
    __builtin_amdgcn_s_setprio(1);
#pragma unroll
    for (int ks = 0; ks < 7; ks++) {
      uint4 aw;
      aw.x = P2[2 * ks][0];
      aw.y = P2[2 * ks][1];
      aw.z = (ks < 6) ? P2[2 * ks + 1][0] : 0u;
      aw.w = (ks < 6) ? P2[2 * ks + 1][1] : 0u;
      const bf16x8 af = __builtin_bit_cast(bf16x8, aw);
      const int cb = ks * 4 + quad;       // kappa chunk
#pragma unroll
      for (int nt = 0; nt < 4; nt++) {
        const int d = nt * 16 + l15;
        const int p = (d >> 3) & 7;
        const int chs = (cb < 24) ? ((cb & 24) | ((cb & 7) ^ p)) : cb;
        bf16x8 bv = *(const bf16x8*)(Vt + d * 224 + chs * 8);
        oacc[nt] = mfma16(af, bv, oacc[nt]);
      }
    }
    __builtin_amdgcn_s_setprio(0);
  }

  const int b = bh / NH, head = bh - b * NH;
#pragma unroll
  for (int nt = 0; nt < 4; nt++) {
#pragma unroll
    for (int rg = 0; rg < 4; rg++) {
      const int qro = q0 + wave * 16 + quad * 4 + rg;
      if (qro < HW) {
        const int d = nt * 16 + l15;
        aout[((size_t)b * HW + qro) * HIDDEN + head * 64 + d] = f2bf(oacc[nt][rg]);
      }
    }
  }
}

extern "C" void kernel_launch(void* const* d_in, const int* in_sizes, int n_in,
                              void* d_out, int out_size, void* d_ws, size_t ws_size,
                              hipStream_t stream) {
  const float* hidden = (const float*)d_in[0];
  const float* qkv_w = (const float*)d_in[1];
  const float* qkv_b = (const float*)d_in[2];
  const float* proj_w = (const float*)d_in[3];
  const float* proj_b = (const float*)d_in[4];
  const float* rel_h = (const float*)d_in[5];
  const float* rel_w = (const float*)d_in[6];

  uint8_t* ws = (uint8_t*)d_ws;
  uint16_t* Xb = (uint16_t*)(ws);                  // 77,070,336 B; reused as attn_out
  uint16_t* qkvb = (uint16_t*)(ws + 77070336);     // 231,211,008 B: [3][3072][196][64] bf16
  uint16_t* Rt = (uint16_t*)(ws + 308281344);      // 8,192 B: [64][64] bf16 rel table
  uint16_t* wqkvb = (uint16_t*)(ws + 308289536);   // 3,538,944 B
  uint16_t* wprjb = (uint16_t*)(ws + 311828480);   // 1,179,648 B

  cvt_bf16<<<4096, 256, 0, stream>>>(hidden, Xb, (MTOT * HIDDEN) / 4);
  cvt_bf16<<<1024, 256, 0, stream>>>(qkv_w, wqkvb, (3 * HIDDEN * HIDDEN) / 4);
  cvt_bf16<<<576, 256, 0, stream>>>(proj_w, wprjb, (HIDDEN * HIDDEN) / 4);
  build_rt<<<16, 256, 0, stream>>>(rel_h, rel_w, Rt);

  gemm_bt<0><<<dim3(18, 392), 256, 0, stream>>>(Xb, wqkvb, qkv_b, (void*)qkvb);
  attn_kernel<<<dim3(12288), 256, 0, stream>>>(qkvb, Rt, Xb);
  gemm_bt<1><<<dim3(6, 392), 256, 0, stream>>>(Xb, wprjb, proj_b, d_out);
}

// Round 2
// 749.489 us; speedup vs baseline: 1.3131x; 1.0715x over previous
//
#include <hip/hip_runtime.h>
#include <stdint.h>

#define WIN 14
#define HW 196
#define NH 12
#define HIDDEN 768
#define BH 3072
#define MTOT 50176
#define KDIM 768

typedef __bf16 bf16x8 __attribute__((ext_vector_type(8)));
typedef float f32x4 __attribute__((ext_vector_type(4)));

__device__ __forceinline__ float bf2f(uint16_t u) {
  union { uint32_t i; float f; } v; v.i = ((uint32_t)u) << 16; return v.f;
}
__device__ __forceinline__ uint16_t f2bf(float f) {
  uint32_t u = __float_as_uint(f);
  uint32_t r = u + 0x7FFFu + ((u >> 16) & 1u);
  return (uint16_t)(r >> 16);
}
__device__ __forceinline__ uint32_t pack2bf(float a, float b) {
  return (uint32_t)f2bf(a) | ((uint32_t)f2bf(b) << 16);
}
__device__ __forceinline__ f32x4 mfma16(bf16x8 a, bf16x8 b, f32x4 c) {
  return __builtin_amdgcn_mfma_f32_16x16x32_bf16(a, b, c, 0, 0, 0);
}
__device__ __forceinline__ f32x4 f4zero() { f32x4 z = {0.f, 0.f, 0.f, 0.f}; return z; }

__device__ __forceinline__ void async16(const void* g, void* l) {
#if __has_builtin(__builtin_amdgcn_global_load_lds)
  __builtin_amdgcn_global_load_lds((__attribute__((address_space(1))) void*)g,
                                   (__attribute__((address_space(3))) void*)l, 16, 0, 0);
#else
  *(uint4*)l = *(const uint4*)g;
#endif
}

// ---------------- fp32 -> bf16 convert ----------------
__global__ __launch_bounds__(256) void cvt_bf16(const float* __restrict__ in,
                                                uint16_t* __restrict__ out, int n4) {
  int i = blockIdx.x * blockDim.x + threadIdx.x;
  const int stride = gridDim.x * blockDim.x;
  for (; i < n4; i += stride) {
    float4 v = ((const float4*)in)[i];
    ushort4 o;
    o.x = f2bf(v.x); o.y = f2bf(v.y); o.z = f2bf(v.z); o.w = f2bf(v.w);
    ((ushort4*)out)[i] = o;
  }
}

// ---------------- build rel-pos B-operand table: Rt[64][64] bf16 ----------------
__global__ __launch_bounds__(256) void build_rt(const float* __restrict__ rh,
                                                const float* __restrict__ rw,
                                                uint16_t* __restrict__ Rt) {
  const int i = blockIdx.x * 256 + threadIdx.x;
  if (i < 4096) {
    const int r = i >> 6, c = i & 63;
    float v = 0.f;
    if (r < 27) v = rh[r * 64 + c] * 8.f;
    else if (r >= 32 && r < 59) v = rw[(r - 32) * 64 + c] * 8.f;
    Rt[i] = f2bf(v);
  }
}

// ---------------- GEMM: C[m][n] = sum_k A[m][k]*B[n][k] (+bias), bf16 in, K=768 ----
// 256x256 tile, BK=32, 8 waves (2M x 4N, 128x64 per wave), TRIPLE-buffered LDS.
// Counted-vmcnt pipeline: tile t's loads issued during tile t-2; boundary wait is
// s_waitcnt vmcnt(4) (tile t+1's 4 loads stay in flight) + raw s_barrier. One
// barrier per K-tile, never a vmcnt(0) drain in the main loop (T3+T4), setprio
// around MFMA clusters (T5). LDS chunk swizzle: ch ^= (r>>1)&3 (2-way = free),
// applied inverse on the global source (linear gload_lds dest) and on ds_reads.
template <int EPI>
__global__ __launch_bounds__(512, 2) void gemm_bt(const uint16_t* __restrict__ A,
                                                  const uint16_t* __restrict__ B,
                                                  const float* __restrict__ bias,
                                                  void* __restrict__ outp) {
  __shared__ __align__(16) uint16_t lds[6 * 8192];  // A bufs [3][8192], B bufs [3][8192]
  uint16_t* Asb = lds;
  uint16_t* Bsb = lds + 3 * 8192;

  const int tid = threadIdx.x;
  const int nbx = gridDim.x;
  const int nwg = nbx * gridDim.y;
  const int orig = blockIdx.y * nbx + blockIdx.x;
  // bijective XCD swizzle (m204 form; nwg not necessarily % 8)
  const int xcd = orig & 7, rr = nwg & 7, qq = nwg >> 3;
  const int idr = (xcd < rr ? xcd * (qq + 1) : rr * (qq + 1) + (xcd - rr) * qq) + (orig >> 3);
  const int tile_n = (idr % nbx) * 256;
  const int tile_m = (idr / nbx) * 256;

  const int lane = tid & 63;
  const int wave = tid >> 6;
  const int l15 = lane & 15, quad = lane >> 4;
  const int wr = wave >> 2, wc = wave & 3;
  const int wm = wr * 128, wn = wc * 64;

  f32x4 acc[8][4];
#pragma unroll
  for (int mi = 0; mi < 8; mi++)
#pragma unroll
    for (int ni = 0; ni < 4; ni++) acc[mi][ni] = f4zero();

  auto STAGE_A = [&](int tt, int cb) {
#pragma unroll
    for (int j = 0; j < 2; ++j) {
      const int o = tid * 16 + j * 8192;          // byte offset in 16KB buf
      const int r = o >> 6, ch = (o >> 4) & 3;
      const int c = ch ^ ((r >> 1) & 3);
      async16((const uint8_t*)A + ((size_t)(tile_m + r) * KDIM + tt * 32 + c * 8) * 2,
              (uint8_t*)(Asb + cb * 8192) + o);
    }
  };
  auto STAGE_B = [&](int tt, int cb) {
#pragma unroll
    for (int j = 0; j < 2; ++j) {
      const int o = tid * 16 + j * 8192;
      const int r = o >> 6, ch = (o >> 4) & 3;
      const int c = ch ^ ((r >> 1) & 3);
      async16((const uint8_t*)B + ((size_t)(tile_n + r) * KDIM + tt * 32 + c * 8) * 2,
              (uint8_t*)(Bsb + cb * 8192) + o);
    }
  };

  const int NT = KDIM / 32;  // 24
  STAGE_A(0, 0); STAGE_B(0, 0);
  STAGE_A(1, 1); STAGE_B(1, 1);

  int cur = 0;
  for (int t = 0; t < NT; ++t) {
    // boundary: tile t's 4 loads (issued at t-2) must be done; t+1's may fly.
    if (t + 1 < NT) {
      asm volatile("s_waitcnt vmcnt(4)" ::: "memory");
    } else {
      asm volatile("s_waitcnt vmcnt(0)" ::: "memory");
    }
    __builtin_amdgcn_s_barrier();
    __builtin_amdgcn_sched_barrier(0);

    const uint16_t* Ab = Asb + cur * 8192;
    const uint16_t* Bb = Bsb + cur * 8192;
    const int nxt2 = (cur == 0) ? 2 : cur - 1;     // (cur+2)%3

    // ---- phase 0: stage A(t+2) | read B frags + A frags mi0-3 | 16 MFMA
    if (t + 2 < NT) STAGE_A(t + 2, nxt2);
    bf16x8 bfr[4];
#pragma unroll
    for (int ni = 0; ni < 4; ni++) {
      const int r = wn + ni * 16 + l15;
      const int c = quad ^ ((r >> 1) & 3);
      bfr[ni] = *(const bf16x8*)(Bb + r * 32 + c * 8);
    }
    bf16x8 af[4];
#pragma unroll
    for (int mi = 0; mi < 4; mi++) {
      const int r = wm + mi * 16 + l15;
      const int c = quad ^ ((r >> 1) & 3);
      af[mi] = *(const bf16x8*)(Ab + r * 32 + c * 8);
    }
    __builtin_amdgcn_s_setprio(1);
#pragma unroll
    for (int mi = 0; mi < 4; mi++)
#pragma unroll
      for (int ni = 0; ni < 4; ni++)
        acc[mi][ni] = mfma16(af[mi], bfr[ni], acc[mi][ni]);
    __builtin_amdgcn_s_setprio(0);

    // ---- phase 1: stage B(t+2) | read A frags mi4-7 | 16 MFMA
    if (t + 2 < NT) STAGE_B(t + 2, nxt2);
#pragma unroll
    for (int mi = 0; mi < 4; mi++) {
      const int r = wm + 64 + mi * 16 + l15;
      const int c = quad ^ ((r >> 1) & 3);
      af[mi] = *(const bf16x8*)(Ab + r * 32 + c * 8);
    }
    __builtin_amdgcn_s_setprio(1);
#pragma unroll
    for (int mi = 0; mi < 4; mi++)
#pragma unroll
      for (int ni = 0; ni < 4; ni++)
        acc[4 + mi][ni] = mfma16(af[mi], bfr[ni], acc[4 + mi][ni]);
    __builtin_amdgcn_s_setprio(0);

    cur = (cur == 2) ? 0 : cur + 1;
  }

#pragma unroll
  for (int mi = 0; mi < 8; mi++) {
#pragma unroll
    for (int ni = 0; ni < 4; ni++) {
#pragma unroll
      for (int rg = 0; rg < 4; rg++) {
        const int m = tile_m + wm + mi * 16 + quad * 4 + rg;
        const int n = tile_n + wn + ni * 16 + l15;
        float v = acc[mi][ni][rg] + bias[n];
        if (EPI == 0) {
          const int which = n / HIDDEN;
          const int rem = n - which * HIDDEN;
          const int head = rem >> 6, d = rem & 63;
          const int b = m / HW;
          const int s = m - b * HW;
          if (which == 0) v *= 0.125f;  // q pre-scaled by hd^-0.5
          ((uint16_t*)outp)[(((size_t)which * BH + (size_t)b * NH + head) * HW + s) * 64 + d] =
              f2bf(v);
        } else {
          ((float*)outp)[(size_t)m * HIDDEN + n] = v;
        }
      }
    }
  }
}

// ---------------- fused attention (swapped-operand form) ----------------
__global__ __launch_bounds__(256, 4) void attn_kernel(const uint16_t* __restrict__ qkv,
                                                      const uint16_t* __restrict__ Rt,
                                                      uint16_t* __restrict__ aout) {
  __shared__ __align__(16) uint8_t smem[37376];
  uint16_t* Ks = (uint16_t*)smem;              // [208][64] chunk-swizzled
  uint16_t* Vt = (uint16_t*)smem;              // [64][224] kappa-order, chunk-swizzled
  uint16_t* Ts = (uint16_t*)(smem + 28672);    // [64][68]: T^T[r][q_local]

  const int wgid = blockIdx.x;                 // 0..12287
  const int jsw = (wgid & 7) * 1536 + (wgid >> 3);  // XCD swizzle (12288 % 8 == 0)
  const int qt = jsw & 3;
  const int bh = jsw >> 2;
  const int q0 = qt * 64;
  const int tid = threadIdx.x;
  const int wave = tid >> 6, lane = tid & 63;
  const int l15 = lane & 15, quad = lane >> 4;

  const uint16_t* qg = qkv + (size_t)bh * HW * 64;
  const uint16_t* kg = qkv + ((size_t)BH + bh) * HW * 64;
  const uint16_t* vg = qkv + ((size_t)2 * BH + bh) * HW * 64;

  // ---- stage K -> Ks, chunk-swizzled: (r, chunk c) at r*64 + (c^(r&7))*8
#pragma unroll
  for (int i = 0; i < 7; i++) {
    const int c = tid + i * 256;
    if (c < 1568) {
      const int r = c >> 3, ch = c & 7;
      uint4 v = *(const uint4*)(kg + (size_t)r * 64 + ch * 8);
      *(uint4*)(Ks + r * 64 + ((ch ^ (r & 7)) * 8)) = v;
    }
  }

  // ---- Q fragment straight from global (b-operand: row=l15, chunk=quad)
  const int qrow = q0 + wave * 16 + l15;       // this lane's q row
  const int qr = (qrow < HW) ? qrow : (HW - 1);
  bf16x8 qb0 = *(const bf16x8*)(qg + (size_t)qr * 64 + quad * 8);
  bf16x8 qb1 = *(const bf16x8*)(qg + (size_t)qr * 64 + 32 + quad * 8);

  // ---- T^T = Rt * Q^T : lane holds T^T[r = t*16+quad*4+rg][q=l15]; spill to Ts
  {
    f32x4 racc[4];
#pragma unroll
    for (int t = 0; t < 4; t++) racc[t] = f4zero();
    __builtin_amdgcn_s_setprio(1);
#pragma unroll
    for (int t = 0; t < 4; t++) {
      bf16x8 r0 = *(const bf16x8*)(Rt + (t * 16 + l15) * 64 + quad * 8);
      bf16x8 r1 = *(const bf16x8*)(Rt + (t * 16 + l15) * 64 + 32 + quad * 8);
      racc[t] = mfma16(r0, qb0, racc[t]);
      racc[t] = mfma16(r1, qb1, racc[t]);
    }
    __builtin_amdgcn_s_setprio(0);
#pragma unroll
    for (int t = 0; t < 4; t++)
#pragma unroll
      for (int rg = 0; rg < 4; rg++)
        Ts[(t * 16 + quad * 4 + rg) * 68 + wave * 16 + l15] = f2bf(racc[t][rg]);
  }

  __syncthreads();  // Ks staged (Ts writes also ordered before all later reads)

  // ---- prefetch V into registers (latency hidden under S-phase MFMAs)
  uint4 vreg[7];
#pragma unroll
  for (int i = 0; i < 7; i++) {
    const int c = tid + i * 256;
    vreg[i] = (c < 1568) ? *(const uint4*)(vg + (size_t)c * 8) : make_uint4(0u, 0u, 0u, 0u);
  }

  // ---- S^T = K * Q^T : lane holds S[j = t*16+quad*4+rg][its own q]
  f32x4 sacc[13];
#pragma unroll
  for (int t = 0; t < 13; t++) sacc[t] = f4zero();
  {
    const int sw0 = (quad ^ (l15 & 7)) * 8;
    const int sw1 = ((quad + 4) ^ (l15 & 7)) * 8;
    __builtin_amdgcn_s_setprio(1);
#pragma unroll
    for (int t = 0; t < 13; t++) {
      const uint16_t* kr = Ks + (t * 16 + l15) * 64;
      bf16x8 a0 = *(const bf16x8*)(kr + sw0);
      bf16x8 a1 = *(const bf16x8*)(kr + sw1);
      sacc[t] = mfma16(a0, qb0, sacc[t]);
      sacc[t] = mfma16(a1, qb1, sacc[t]);
    }
    __builtin_amdgcn_s_setprio(0);
  }

  __syncthreads();  // all waves done reading Ks; V loads drained before overlay

  // ---- zero the kappa-tail columns [196,224) of Vt (one store per thread)
  {
    const int d = tid & 63, wv = tid >> 6;
    if (wv == 0) *(uint2*)(Vt + d * 224 + 196) = make_uint2(0u, 0u);
    else *(uint4*)(Vt + d * 224 + 200 + (wv - 1) * 8) = make_uint4(0u, 0u, 0u, 0u);
  }

  // ---- V^T into Vt in kappa-order, swizzled; writes are bank-conflict-free
  // kappa(j): j = t*16 + qj*4 + rg  ->  (t>>1)*32 + qj*8 + (t&1)*4 + rg
#pragma unroll
  for (int i = 0; i < 7; i++) {
    const int c = tid + i * 256;
    if (c < 1568) {
      const int jj = c >> 3;
      const int dp = c & 7;               // d block: rows dp*8 .. dp*8+7
      const int tt = jj >> 4;
      const int kap = (tt >> 1) * 32 + ((jj >> 2) & 3) * 8 + (tt & 1) * 4 + (jj & 3);
      const int cj = kap >> 3;
      const int chs = (cj < 24) ? ((cj & 24) | ((cj & 7) ^ dp)) : cj;
      uint16_t* dst = Vt + dp * 8 * 224 + chs * 8 + (kap & 7);
      const uint16_t* pe = (const uint16_t*)&vreg[i];
#pragma unroll
      for (int e = 0; e < 8; e++) dst[e * 224] = pe[e];
    }
  }

  // ---- softmax fully in registers (row = lane's own q); bias from Ts
  uint32_t P2[13][2];
  {
    const int hq = (qr * 586) >> 13;      // qr / 14
    const int wq = qr - hq * 14;
    const uint16_t* Tb = Ts + wave * 16 + l15;   // column base, rows stride 68
    const int c0 = (hq + 13) * 68;
    const int c1 = (wq + 45) * 68;
    float mx0 = -1e30f, mx1 = -1e30f, mx2 = -1e30f, mx3 = -1e30f;
#pragma unroll
    for (int t = 0; t < 13; t++) {
#pragma unroll
      for (int rg = 0; rg < 4; rg++) {
        const int j = t * 16 + quad * 4 + rg;
        const int kh = (j * 586) >> 13;   // j / 14 (valid for j <= 195)
        const int kw = j - kh * 14;
        const float b = bf2f(Tb[c0 - kh * 68]) + bf2f(Tb[c1 - kw * 68]);
        float s = sacc[t][rg] + b;
        s = (j < HW) ? s : -1e30f;
        sacc[t][rg] = s;
        if (rg == 0) mx0 = fmaxf(mx0, s);
        else if (rg == 1) mx1 = fmaxf(mx1, s);
        else if (rg == 2) mx2 = fmaxf(mx2, s);
        else mx3 = fmaxf(mx3, s);
      }
    }
    float mx = fmaxf(fmaxf(mx0, mx1), fmaxf(mx2, mx3));
    mx = fmaxf(mx, __shfl_xor(mx, 16, 64));
    mx = fmaxf(mx, __shfl_xor(mx, 32, 64));
    float s0 = 0.f, s1 = 0.f, s2 = 0.f, s3 = 0.f;
#pragma unroll
    for (int t = 0; t < 13; t++) {
#pragma unroll
      for (int rg = 0; rg < 4; rg++) {
        const float p = __expf(sacc[t][rg] - mx);
        sacc[t][rg] = p;
        if (rg == 0) s0 += p;
        else if (rg == 1) s1 += p;
        else if (rg == 2) s2 += p;
        else s3 += p;
      }
    }
    float sum = (s0 + s1) + (s2 + s3);
    sum += __shfl_xor(sum, 16, 64);
    sum += __shfl_xor(sum, 32, 64);
    const float inv = 1.f / sum;
#pragma unroll
    for (int t = 0; t < 13; t++) {
      P2[t][0] = pack2bf(sacc[t][0] * inv, sacc[t][1] * inv);
      P2[t][1] = pack2bf(sacc[t][2] * inv, sacc[t][3] * inv);
    }
  }

  __syncthreads();  // all Vt writes visible before PV reads

  // ---- O = P*V : A-fragment is the lane's own P2 registers (kappa order)
  f32x4 oacc[4];
#pragma unroll
  for (int nt = 0; nt < 4; nt++) oacc[nt] = f4zero();
  {
    __builtin_amdgcn_s_setprio(1);
#pragma unroll
    for (int ks = 0; ks < 7; ks++) {
      uint4 aw;
      aw.x = P2[2 * ks][0];
      aw.y = P2[2 * ks][1];
      aw.z = (ks < 6) ? P2[2 * ks + 1][0] : 0u;
      aw.w = (ks < 6) ? P2[2 * ks + 1][1] : 0u;
      const bf16x8 af = __builtin_bit_cast(bf16x8, aw);
      const int cb = ks * 4 + quad;       // kappa chunk
#pragma unroll
      for (int nt = 0; nt < 4; nt++) {
        const int d = nt * 16 + l15;
        const int p = (d >> 3) & 7;
        const int chs = (cb < 24) ? ((cb & 24) | ((cb & 7) ^ p)) : cb;
        bf16x8 bv = *(const bf16x8*)(Vt + d * 224 + chs * 8);
        oacc[nt] = mfma16(af, bv, oacc[nt]);
      }
    }
    __builtin_amdgcn_s_setprio(0);
  }

  const int b = bh / NH, head = bh - b * NH;
#pragma unroll
  for (int nt = 0; nt < 4; nt++) {
#pragma unroll
    for (int rg = 0; rg < 4; rg++) {
      const int qro = q0 + wave * 16 + quad * 4 + rg;
      if (qro < HW) {
        const int d = nt * 16 + l15;
        aout[((size_t)b * HW + qro) * HIDDEN + head * 64 + d] = f2bf(oacc[nt][rg]);
      }
    }
  }
}

extern "C" void kernel_launch(void* const* d_in, const int* in_sizes, int n_in,
                              void* d_out, int out_size, void* d_ws, size_t ws_size,
                              hipStream_t stream) {
  const float* hidden = (const float*)d_in[0];
  const float* qkv_w = (const float*)d_in[1];
  const float* qkv_b = (const float*)d_in[2];
  const float* proj_w = (const float*)d_in[3];
  const float* proj_b = (const float*)d_in[4];
  const float* rel_h = (const float*)d_in[5];
  const float* rel_w = (const float*)d_in[6];

  uint8_t* ws = (uint8_t*)d_ws;
  uint16_t* Xb = (uint16_t*)(ws);                  // 77,070,336 B; reused as attn_out
  uint16_t* qkvb = (uint16_t*)(ws + 77070336);     // 231,211,008 B: [3][3072][196][64] bf16
  uint16_t* Rt = (uint16_t*)(ws + 308281344);      // 8,192 B: [64][64] bf16 rel table
  uint16_t* wqkvb = (uint16_t*)(ws + 308289536);   // 3,538,944 B
  uint16_t* wprjb = (uint16_t*)(ws + 311828480);   // 1,179,648 B

  cvt_bf16<<<4096, 256, 0, stream>>>(hidden, Xb, (MTOT * HIDDEN) / 4);
  cvt_bf16<<<1024, 256, 0, stream>>>(qkv_w, wqkvb, (3 * HIDDEN * HIDDEN) / 4);
  cvt_bf16<<<576, 256, 0, stream>>>(proj_w, wprjb, (HIDDEN * HIDDEN) / 4);
  build_rt<<<16, 256, 0, stream>>>(rel_h, rel_w, Rt);

  gemm_bt<0><<<dim3(9, 196), 512, 0, stream>>>(Xb, wqkvb, qkv_b, (void*)qkvb);
  attn_kernel<<<dim3(12288), 256, 0, stream>>>(qkvb, Rt, Xb);
  gemm_bt<1><<<dim3(3, 196), 512, 0, stream>>>(Xb, wprjb, proj_b, d_out);
}

// Round 3
// 714.802 us; speedup vs baseline: 1.3769x; 1.0485x over previous
//
#include <hip/hip_runtime.h>
#include <stdint.h>

#define WIN 14
#define HW 196
#define NH 12
#define HIDDEN 768
#define BH 3072
#define MTOT 50176
#define KDIM 768

typedef __bf16 bf16x8 __attribute__((ext_vector_type(8)));
typedef float f32x4 __attribute__((ext_vector_type(4)));

__device__ __forceinline__ float bf2f(uint16_t u) {
  union { uint32_t i; float f; } v; v.i = ((uint32_t)u) << 16; return v.f;
}
__device__ __forceinline__ uint16_t f2bf(float f) {
  uint32_t u = __float_as_uint(f);
  uint32_t r = u + 0x7FFFu + ((u >> 16) & 1u);
  return (uint16_t)(r >> 16);
}
__device__ __forceinline__ uint32_t pack2bf(float a, float b) {
  return (uint32_t)f2bf(a) | ((uint32_t)f2bf(b) << 16);
}
__device__ __forceinline__ f32x4 mfma16(bf16x8 a, bf16x8 b, f32x4 c) {
  return __builtin_amdgcn_mfma_f32_16x16x32_bf16(a, b, c, 0, 0, 0);
}
__device__ __forceinline__ f32x4 f4zero() { f32x4 z = {0.f, 0.f, 0.f, 0.f}; return z; }

__device__ __forceinline__ void async16(const void* g, void* l) {
#if __has_builtin(__builtin_amdgcn_global_load_lds)
  __builtin_amdgcn_global_load_lds((__attribute__((address_space(1))) void*)g,
                                   (__attribute__((address_space(3))) void*)l, 16, 0, 0);
#else
  *(uint4*)l = *(const uint4*)g;
#endif
}

// ---------------- fp32 -> bf16 convert ----------------
__global__ __launch_bounds__(256) void cvt_bf16(const float* __restrict__ in,
                                                uint16_t* __restrict__ out, int n4) {
  int i = blockIdx.x * blockDim.x + threadIdx.x;
  const int stride = gridDim.x * blockDim.x;
  for (; i < n4; i += stride) {
    float4 v = ((const float4*)in)[i];
    ushort4 o;
    o.x = f2bf(v.x); o.y = f2bf(v.y); o.z = f2bf(v.z); o.w = f2bf(v.w);
    ((ushort4*)out)[i] = o;
  }
}

// ---------------- build rel-pos B-operand table: Rt[64][64] bf16 ----------------
__global__ __launch_bounds__(256) void build_rt(const float* __restrict__ rh,
                                                const float* __restrict__ rw,
                                                uint16_t* __restrict__ Rt) {
  const int i = blockIdx.x * 256 + threadIdx.x;
  if (i < 4096) {
    const int r = i >> 6, c = i & 63;
    float v = 0.f;
    if (r < 27) v = rh[r * 64 + c] * 8.f;
    else if (r >= 32 && r < 59) v = rw[(r - 32) * 64 + c] * 8.f;
    Rt[i] = f2bf(v);
  }
}

// ---------------- GEMM: C[m][n] = sum_k A[m][k]*B[n][k] (+bias), bf16 in, K=768 ----
// 256x256 tile, BK=64, 8 waves (2M x 4N), 8-phase double-barrier schedule (T3+T4+T5).
// LDS = 8 half-tile slots of 16KB (A halves: slots 0..3, B halves: 4..7) = 128 KB.
// Iteration processes K-tiles S (slots 0,1 / 4,5) and S+1 (slots 2,3 / 6,7) in
// 8 phases; each phase = {ds_reads | stage 1 half-tile -> barrier -> lgkmcnt(0) ->
// 16 MFMA -> barrier}. B-fragments register-cached per K-tile (read in phase 0/4).
// Stage placement (race-free: stage of slot X issues >=1 end-barrier after X's
// last read): P0:A2<-S+1h0, P1:A3<-S+1h1, P2:B0<-S+2h0, P3:B1<-S+2h1,
// P4:A0<-S+2h0, P5:A1<-S+2h1, P6:B2<-S+3h0, P7:B3<-S+3h1.
// Counted waits: vmcnt(4) at end of P3 and P7 only (2 newest halves may fly).
// Swizzle: chunk c at row r stored at c^(r&7); applied inverse on global source
// (linear global_load_lds dest); read offsets are loop-invariant (rA&7 == l15&7).
template <int EPI>
__global__ __launch_bounds__(512, 2) void gemm_bt(const uint16_t* __restrict__ A,
                                                  const uint16_t* __restrict__ B,
                                                  const float* __restrict__ bias,
                                                  void* __restrict__ outp) {
  __shared__ __align__(16) uint16_t lds[8 * 8192];  // 128 KB

  const int tid = threadIdx.x;
  const int nbx = gridDim.x;
  const int nwg = nbx * gridDim.y;
  const int orig = blockIdx.y * nbx + blockIdx.x;
  // bijective XCD swizzle (m204 form)
  const int xcd = orig & 7, rr = nwg & 7, qq = nwg >> 3;
  const int idr = (xcd < rr ? xcd * (qq + 1) : rr * (qq + 1) + (xcd - rr) * qq) + (orig >> 3);
  const int tile_n = (idr % nbx) * 256;
  const int tile_m = (idr / nbx) * 256;

  const int lane = tid & 63;
  const int wave = tid >> 6;
  const int l15 = lane & 15, quad = lane >> 4;
  const int wr = wave >> 2, wc = wave & 3;
  const int wm = wr * 128, wn = wc * 64;

  f32x4 acc[8][4];
#pragma unroll
  for (int mi = 0; mi < 8; mi++)
#pragma unroll
    for (int ni = 0; ni < 4; ni++) acc[mi][ni] = f4zero();

  // per-thread staging geometry (loop-invariant)
  const int st_r = tid >> 3;                       // row within first 8KB chunk group
  const int st_c = (tid & 7) ^ (st_r & 7);         // logical chunk feeding this dest

  auto STAGE = [&](const uint16_t* src, int rowbase, int kt, int slot) {
#pragma unroll
    for (int jj = 0; jj < 2; ++jj) {
      const int row = rowbase + st_r + jj * 64;
      async16(src + (size_t)row * KDIM + kt * 64 + st_c * 8,
              (uint8_t*)(lds + slot * 8192) + tid * 16 + jj * 8192);
    }
  };

  // loop-invariant fragment-read swizzle offsets (rA&7 == rB&7 == l15&7)
  const int sw0 = (quad ^ (l15 & 7)) * 8;
  const int sw1 = ((4 + quad) ^ (l15 & 7)) * 8;
  const uint16_t* Aslot = lds + (size_t)wr * 8192;
  const uint16_t* Bslot = lds + (size_t)(4 + (wc >> 1)) * 8192;
  const int rBb = (wc & 1) * 64;

  // prologue: tile0 A+B, tile1 B; allow tile1's B halves (4 loads) to fly
  STAGE(A, tile_m, 0, 0);
  STAGE(A, tile_m + 128, 0, 1);
  STAGE(B, tile_n, 0, 4);
  STAGE(B, tile_n + 128, 0, 5);
  STAGE(B, tile_n, 1, 6);
  STAGE(B, tile_n + 128, 1, 7);
  asm volatile("s_waitcnt vmcnt(4)" ::: "memory");
  __builtin_amdgcn_s_barrier();

  const int NIT = KDIM / 128;  // 6
  for (int j = 0; j < NIT; ++j) {
    const int S = 2 * j;
    const bool stg = (j < NIT - 1);
#pragma unroll
    for (int pb = 0; pb < 2; ++pb) {
      bf16x8 bfr[4][2];
#pragma unroll
      for (int q = 0; q < 4; ++q) {
        // ---- ds reads for this phase
        if (q == 0) {
#pragma unroll
          for (int ni = 0; ni < 4; ++ni) {
            const int rB = rBb + ni * 16 + l15;
            const uint16_t* bp = Bslot + pb * 16384 + rB * 64;
            bfr[ni][0] = *(const bf16x8*)(bp + sw0);
            bfr[ni][1] = *(const bf16x8*)(bp + sw1);
          }
        }
        bf16x8 af[2][2];
#pragma unroll
        for (int m2 = 0; m2 < 2; ++m2) {
          const int rA = (q * 2 + m2) * 16 + l15;
          const uint16_t* ap = Aslot + pb * 16384 + rA * 64;
          af[m2][0] = *(const bf16x8*)(ap + sw0);
          af[m2][1] = *(const bf16x8*)(ap + sw1);
        }
        // ---- stage one half-tile per schedule
        if (pb == 0) {
          if (q == 0) STAGE(A, tile_m, S + 1, 2);
          else if (q == 1) STAGE(A, tile_m + 128, S + 1, 3);
          else if (q == 2) { if (stg) STAGE(B, tile_n, S + 2, 4); }
          else { if (stg) STAGE(B, tile_n + 128, S + 2, 5); }
        } else {
          if (q == 0) { if (stg) STAGE(A, tile_m, S + 2, 0); }
          else if (q == 1) { if (stg) STAGE(A, tile_m + 128, S + 2, 1); }
          else if (q == 2) { if (stg) STAGE(B, tile_n, S + 3, 6); }
          else { if (stg) STAGE(B, tile_n + 128, S + 3, 7); }
        }
        __builtin_amdgcn_s_barrier();
        asm volatile("s_waitcnt lgkmcnt(0)" ::: "memory");
        __builtin_amdgcn_sched_barrier(0);
        __builtin_amdgcn_s_setprio(1);
#pragma unroll
        for (int kk = 0; kk < 2; ++kk)
#pragma unroll
          for (int m2 = 0; m2 < 2; ++m2)
#pragma unroll
            for (int ni = 0; ni < 4; ++ni)
              acc[q * 2 + m2][ni] = mfma16(af[m2][kk], bfr[ni][kk], acc[q * 2 + m2][ni]);
        __builtin_amdgcn_s_setprio(0);
        if (q == 3) {
          if (stg) asm volatile("s_waitcnt vmcnt(4)" ::: "memory");
          else asm volatile("s_waitcnt vmcnt(0)" ::: "memory");
        }
        __builtin_amdgcn_s_barrier();
      }
    }
  }

#pragma unroll
  for (int mi = 0; mi < 8; mi++) {
#pragma unroll
    for (int ni = 0; ni < 4; ni++) {
#pragma unroll
      for (int rg = 0; rg < 4; rg++) {
        const int m = tile_m + wm + mi * 16 + quad * 4 + rg;
        const int n = tile_n + wn + ni * 16 + l15;
        float v = acc[mi][ni][rg] + bias[n];
        if (EPI == 0) {
          const int which = n / HIDDEN;
          const int rem = n - which * HIDDEN;
          const int head = rem >> 6, d = rem & 63;
          const int b = m / HW;
          const int s = m - b * HW;
          if (which == 0) v *= 0.125f;  // q pre-scaled by hd^-0.5
          ((uint16_t*)outp)[(((size_t)which * BH + (size_t)b * NH + head) * HW + s) * 64 + d] =
              f2bf(v);
        } else {
          ((float*)outp)[(size_t)m * HIDDEN + n] = v;
        }
      }
    }
  }
}

// ---------------- fused attention (swapped-operand form) ----------------
__global__ __launch_bounds__(256, 4) void attn_kernel(const uint16_t* __restrict__ qkv,
                                                      const uint16_t* __restrict__ Rt,
                                                      uint16_t* __restrict__ aout) {
  __shared__ __align__(16) uint8_t smem[37376];
  uint16_t* Ks = (uint16_t*)smem;              // [208][64] chunk-swizzled
  uint16_t* Vt = (uint16_t*)smem;              // [64][224] kappa-order, chunk-swizzled
  uint16_t* Ts = (uint16_t*)(smem + 28672);    // [64][68]: T^T[r][q_local]

  const int wgid = blockIdx.x;                 // 0..12287
  const int jsw = (wgid & 7) * 1536 + (wgid >> 3);  // XCD swizzle (12288 % 8 == 0)
  const int qt = jsw & 3;
  const int bh = jsw >> 2;
  const int q0 = qt * 64;
  const int tid = threadIdx.x;
  const int wave = tid >> 6, lane = tid & 63;
  const int l15 = lane & 15, quad = lane >> 4;

  const uint16_t* qg = qkv + (size_t)bh * HW * 64;
  const uint16_t* kg = qkv + ((size_t)BH + bh) * HW * 64;
  const uint16_t* vg = qkv + ((size_t)2 * BH + bh) * HW * 64;

  // ---- stage K -> Ks, chunk-swizzled: (r, chunk c) at r*64 + (c^(r&7))*8
#pragma unroll
  for (int i = 0; i < 7; i++) {
    const int c = tid + i * 256;
    if (c < 1568) {
      const int r = c >> 3, ch = c & 7;
      uint4 v = *(const uint4*)(kg + (size_t)r * 64 + ch * 8);
      *(uint4*)(Ks + r * 64 + ((ch ^ (r & 7)) * 8)) = v;
    }
  }

  // ---- Q fragment straight from global (b-operand: row=l15, chunk=quad)
  const int qrow = q0 + wave * 16 + l15;       // this lane's q row
  const int qr = (qrow < HW) ? qrow : (HW - 1);
  bf16x8 qb0 = *(const bf16x8*)(qg + (size_t)qr * 64 + quad * 8);
  bf16x8 qb1 = *(const bf16x8*)(qg + (size_t)qr * 64 + 32 + quad * 8);

  // ---- T^T = Rt * Q^T : lane holds T^T[r = t*16+quad*4+rg][q=l15]; spill to Ts
  {
    f32x4 racc[4];
#pragma unroll
    for (int t = 0; t < 4; t++) racc[t] = f4zero();
    __builtin_amdgcn_s_setprio(1);
#pragma unroll
    for (int t = 0; t < 4; t++) {
      bf16x8 r0 = *(const bf16x8*)(Rt + (t * 16 + l15) * 64 + quad * 8);
      bf16x8 r1 = *(const bf16x8*)(Rt + (t * 16 + l15) * 64 + 32 + quad * 8);
      racc[t] = mfma16(r0, qb0, racc[t]);
      racc[t] = mfma16(r1, qb1, racc[t]);
    }
    __builtin_amdgcn_s_setprio(0);
#pragma unroll
    for (int t = 0; t < 4; t++)
#pragma unroll
      for (int rg = 0; rg < 4; rg++)
        Ts[(t * 16 + quad * 4 + rg) * 68 + wave * 16 + l15] = f2bf(racc[t][rg]);
  }

  __syncthreads();  // Ks staged (Ts writes also ordered before all later reads)

  // ---- prefetch V into registers (latency hidden under S-phase MFMAs)
  uint4 vreg[7];
#pragma unroll
  for (int i = 0; i < 7; i++) {
    const int c = tid + i * 256;
    vreg[i] = (c < 1568) ? *(const uint4*)(vg + (size_t)c * 8) : make_uint4(0u, 0u, 0u, 0u);
  }

  // ---- S^T = K * Q^T : lane holds S[j = t*16+quad*4+rg][its own q]
  f32x4 sacc[13];
#pragma unroll
  for (int t = 0; t < 13; t++) sacc[t] = f4zero();
  {
    const int sw0 = (quad ^ (l15 & 7)) * 8;
    const int sw1 = ((quad + 4) ^ (l15 & 7)) * 8;
    __builtin_amdgcn_s_setprio(1);
#pragma unroll
    for (int t = 0; t < 13; t++) {
      const uint16_t* kr = Ks + (t * 16 + l15) * 64;
      bf16x8 a0 = *(const bf16x8*)(kr + sw0);
      bf16x8 a1 = *(const bf16x8*)(kr + sw1);
      sacc[t] = mfma16(a0, qb0, sacc[t]);
      sacc[t] = mfma16(a1, qb1, sacc[t]);
    }
    __builtin_amdgcn_s_setprio(0);
  }

  __syncthreads();  // all waves done reading Ks; V loads drained before overlay

  // ---- zero the kappa-tail columns [196,224) of Vt (one store per thread)
  {
    const int d = tid & 63, wv = tid >> 6;
    if (wv == 0) *(uint2*)(Vt + d * 224 + 196) = make_uint2(0u, 0u);
    else *(uint4*)(Vt + d * 224 + 200 + (wv - 1) * 8) = make_uint4(0u, 0u, 0u, 0u);
  }

  // ---- V^T into Vt in kappa-order, swizzled; writes are bank-conflict-free
  // kappa(j): j = t*16 + qj*4 + rg  ->  (t>>1)*32 + qj*8 + (t&1)*4 + rg
#pragma unroll
  for (int i = 0; i < 7; i++) {
    const int c = tid + i * 256;
    if (c < 1568) {
      const int jj = c >> 3;
      const int dp = c & 7;               // d block: rows dp*8 .. dp*8+7
      const int tt = jj >> 4;
      const int kap = (tt >> 1) * 32 + ((jj >> 2) & 3) * 8 + (tt & 1) * 4 + (jj & 3);
      const int cj = kap >> 3;
      const int chs = (cj < 24) ? ((cj & 24) | ((cj & 7) ^ dp)) : cj;
      uint16_t* dst = Vt + dp * 8 * 224 + chs * 8 + (kap & 7);
      const uint16_t* pe = (const uint16_t*)&vreg[i];
#pragma unroll
      for (int e = 0; e < 8; e++) dst[e * 224] = pe[e];
    }
  }

  // ---- softmax fully in registers (row = lane's own q); bias from Ts
  uint32_t P2[13][2];
  {
    const int hq = (qr * 586) >> 13;      // qr / 14
    const int wq = qr - hq * 14;
    const uint16_t* Tb = Ts + wave * 16 + l15;   // column base, rows stride 68
    const int c0 = (hq + 13) * 68;
    const int c1 = (wq + 45) * 68;
    float mx0 = -1e30f, mx1 = -1e30f, mx2 = -1e30f, mx3 = -1e30f;
#pragma unroll
    for (int t = 0; t < 13; t++) {
#pragma unroll
      for (int rg = 0; rg < 4; rg++) {
        const int j = t * 16 + quad * 4 + rg;
        const int kh = (j * 586) >> 13;   // j / 14 (valid for j <= 195)
        const int kw = j - kh * 14;
        const float b = bf2f(Tb[c0 - kh * 68]) + bf2f(Tb[c1 - kw * 68]);
        float s = sacc[t][rg] + b;
        s = (j < HW) ? s : -1e30f;
        sacc[t][rg] = s;
        if (rg == 0) mx0 = fmaxf(mx0, s);
        else if (rg == 1) mx1 = fmaxf(mx1, s);
        else if (rg == 2) mx2 = fmaxf(mx2, s);
        else mx3 = fmaxf(mx3, s);
      }
    }
    float mx = fmaxf(fmaxf(mx0, mx1), fmaxf(mx2, mx3));
    mx = fmaxf(mx, __shfl_xor(mx, 16, 64));
    mx = fmaxf(mx, __shfl_xor(mx, 32, 64));
    float s0 = 0.f, s1 = 0.f, s2 = 0.f, s3 = 0.f;
#pragma unroll
    for (int t = 0; t < 13; t++) {
#pragma unroll
      for (int rg = 0; rg < 4; rg++) {
        const float p = __expf(sacc[t][rg] - mx);
        sacc[t][rg] = p;
        if (rg == 0) s0 += p;
        else if (rg == 1) s1 += p;
        else if (rg == 2) s2 += p;
        else s3 += p;
      }
    }
    float sum = (s0 + s1) + (s2 + s3);
    sum += __shfl_xor(sum, 16, 64);
    sum += __shfl_xor(sum, 32, 64);
    const float inv = 1.f / sum;
#pragma unroll
    for (int t = 0; t < 13; t++) {
      P2[t][0] = pack2bf(sacc[t][0] * inv, sacc[t][1] * inv);
      P2[t][1] = pack2bf(sacc[t][2] * inv, sacc[t][3] * inv);
    }
  }

  __syncthreads();  // all Vt writes visible before PV reads

  // ---- O = P*V : A-fragment is the lane's own P2 registers (kappa order)
  f32x4 oacc[4];
#pragma unroll
  for (int nt = 0; nt < 4; nt++) oacc[nt] = f4zero();
  {
    __builtin_amdgcn_s_setprio(1);
#pragma unroll
    for (int ks = 0; ks < 7; ks++) {
      uint4 aw;
      aw.x = P2[2 * ks][0];
      aw.y = P2[2 * ks][1];
      aw.z = (ks < 6) ? P2[2 * ks + 1][0] : 0u;
      aw.w = (ks < 6) ? P2[2 * ks + 1][1] : 0u;
      const bf16x8 af = __builtin_bit_cast(bf16x8, aw);
      const int cb = ks * 4 + quad;       // kappa chunk
#pragma unroll
      for (int nt = 0; nt < 4; nt++) {
        const int d = nt * 16 + l15;
        const int p = (d >> 3) & 7;
        const int chs = (cb < 24) ? ((cb & 24) | ((cb & 7) ^ p)) : cb;
        bf16x8 bv = *(const bf16x8*)(Vt + d * 224 + chs * 8);
        oacc[nt] = mfma16(af, bv, oacc[nt]);
      }
    }
    __builtin_amdgcn_s_setprio(0);
  }

  const int b = bh / NH, head = bh - b * NH;
#pragma unroll
  for (int nt = 0; nt < 4; nt++) {
#pragma unroll
    for (int rg = 0; rg < 4; rg++) {
      const int qro = q0 + wave * 16 + quad * 4 + rg;
      if (qro < HW) {
        const int d = nt * 16 + l15;
        aout[((size_t)b * HW + qro) * HIDDEN + head * 64 + d] = f2bf(oacc[nt][rg]);
      }
    }
  }
}

extern "C" void kernel_launch(void* const* d_in, const int* in_sizes, int n_in,
                              void* d_out, int out_size, void* d_ws, size_t ws_size,
                              hipStream_t stream) {
  const float* hidden = (const float*)d_in[0];
  const float* qkv_w = (const float*)d_in[1];
  const float* qkv_b = (const float*)d_in[2];
  const float* proj_w = (const float*)d_in[3];
  const float* proj_b = (const float*)d_in[4];
  const float* rel_h = (const float*)d_in[5];
  const float* rel_w = (const float*)d_in[6];

  uint8_t* ws = (uint8_t*)d_ws;
  uint16_t* Xb = (uint16_t*)(ws);                  // 77,070,336 B; reused as attn_out
  uint16_t* qkvb = (uint16_t*)(ws + 77070336);     // 231,211,008 B: [3][3072][196][64] bf16
  uint16_t* Rt = (uint16_t*)(ws + 308281344);      // 8,192 B: [64][64] bf16 rel table
  uint16_t* wqkvb = (uint16_t*)(ws + 308289536);   // 3,538,944 B
  uint16_t* wprjb = (uint16_t*)(ws + 311828480);   // 1,179,648 B

  cvt_bf16<<<4096, 256, 0, stream>>>(hidden, Xb, (MTOT * HIDDEN) / 4);
  cvt_bf16<<<1024, 256, 0, stream>>>(qkv_w, wqkvb, (3 * HIDDEN * HIDDEN) / 4);
  cvt_bf16<<<576, 256, 0, stream>>>(proj_w, wprjb, (HIDDEN * HIDDEN) / 4);
  build_rt<<<16, 256, 0, stream>>>(rel_h, rel_w, Rt);

  gemm_bt<0><<<dim3(9, 196), 512, 0, stream>>>(Xb, wqkvb, qkv_b, (void*)qkvb);
  attn_kernel<<<dim3(12288), 256, 0, stream>>>(qkvb, Rt, Xb);
  gemm_bt<1><<<dim3(3, 196), 512, 0, stream>>>(Xb, wprjb, proj_b, d_out);
}